// Round 7
// baseline (633.029 us; speedup 1.0000x reference)
//
#include <hip/hip_runtime.h>
#include <math.h>

#define DM   768
#define DI   1536
#define NDS  16
#define DTR  48
#define XDC  80
#define NB   2
#define SEQL 512
#define NT   (NB*SEQL)
#define CC   64
#define TT   8
#define BETA 0.9f
#define NSA  3.4445f
#define NSB  (-4.775f)
#define NSC  2.0315f
#define LOG2E 1.4426950408889634f

typedef __attribute__((ext_vector_type(8))) short short8v;
typedef __attribute__((ext_vector_type(4))) float f32x4;

__device__ __forceinline__ float silu_(float x){ return x / (1.f + __expf(-x)); }
__device__ __forceinline__ unsigned short bfr(float x){
  unsigned u = __float_as_uint(x);
  return (unsigned short)((u + 0x7fffu + ((u>>16)&1u)) >> 16);
}
__device__ __forceinline__ void gl_lds16(const unsigned short* g, unsigned short* l){
  __builtin_amdgcn_global_load_lds((const __attribute__((address_space(1))) void*)g,
                                   (__attribute__((address_space(3))) void*)l, 16, 0, 0);
}

// ---------------- rmsnorm: one block per token; BF=1 -> bf16 output ----------------
template<int BF>
__global__ void rms_k(const float* __restrict__ X, const float* __restrict__ W,
                      void* __restrict__ Ov)
{
  const int g = blockIdx.x, tid = threadIdx.x;
  const float* xr = X + (size_t)g*DM;
  float x0 = xr[tid], x1 = xr[tid+256], x2 = xr[tid+512];
  float ss = x0*x0 + x1*x1 + x2*x2;
  #pragma unroll
  for (int m=1; m<=32; m<<=1) ss += __shfl_xor(ss, m);
  __shared__ float ws[4];
  if ((tid & 63) == 0) ws[tid>>6] = ss;
  __syncthreads();
  float sc = rsqrtf((ws[0]+ws[1]+ws[2]+ws[3])*(1.f/DM) + 1e-5f);
  if (BF){
    unsigned short* o = (unsigned short*)Ov + (size_t)g*DM;
    o[tid]     = bfr(x0*sc*W[tid]);
    o[tid+256] = bfr(x1*sc*W[tid+256]);
    o[tid+512] = bfr(x2*sc*W[tid+512]);
  } else {
    float* o = (float*)Ov + (size_t)g*DM;
    o[tid]     = x0*sc*W[tid];
    o[tid+256] = x1*sc*W[tid+256];
    o[tid+512] = x2*sc*W[tid+512];
  }
}

// ---------------- f32 -> bf16 cast (vectorized) ----------------
__global__ void castbf_k(const float* __restrict__ in, unsigned short* __restrict__ out, int n4)
{
  const int i = blockIdx.x*256 + threadIdx.x;
  if (i >= n4) return;
  float4 v = ((const float4*)in)[i];
  ushort4 o;
  o.x = bfr(v.x); o.y = bfr(v.y); o.z = bfr(v.z); o.w = bfr(v.w);
  ((ushort4*)out)[i] = o;
}

// ---------------- bf16 MFMA GEMM (m97 structure): C = A * B^T ----------------
template<int EPI>
__global__ __launch_bounds__(256) void gemm_mf(
    const unsigned short* __restrict__ Abf, int lda,
    const unsigned short* __restrict__ Bbf, int ldb,
    float* __restrict__ Out, float* __restrict__ Part,
    int M, int N, int K, int SK)
{
  __shared__ unsigned short As[128*32];
  __shared__ unsigned short Bs[128*32];
  const int tid  = threadIdx.x;
  const int wid  = tid >> 6, lane = tid & 63;
  const int bm   = blockIdx.y*128, bn = blockIdx.x*128;
  const int kc   = K/SK, kBeg = blockIdx.z*kc, kEnd = kBeg + kc;
  const int wr   = (wid>>1)*64, wc = (wid&1)*64;

  f32x4 acc[4][4];
  #pragma unroll
  for (int m=0;m<4;m++)
    #pragma unroll
    for (int n=0;n<4;n++) acc[m][n] = (f32x4){0.f,0.f,0.f,0.f};

  const int e0 = (wid*2)*512 + lane*8;
  const int e1 = e0 + 512;
  const int r0 = e0 >> 5, k0e = e0 & 31;
  const int r1 = e1 >> 5, k1e = e1 & 31;
  const unsigned short* Ag0 = Abf + (size_t)(bm + r0)*lda + k0e;
  const unsigned short* Ag1 = Abf + (size_t)(bm + r1)*lda + k1e;
  const unsigned short* Bg0 = Bbf + (size_t)(bn + r0)*ldb + k0e;
  const unsigned short* Bg1 = Bbf + (size_t)(bn + r1)*ldb + k1e;

  int aoff[4], boff[4];
  #pragma unroll
  for (int m=0;m<4;m++) aoff[m] = (wr + m*16 + (lane&15))*32 + (lane>>4)*8;
  #pragma unroll
  for (int n=0;n<4;n++) boff[n] = (wc + n*16 + (lane&15))*32 + (lane>>4)*8;

  for (int k0 = kBeg; k0 < kEnd; k0 += 32){
    gl_lds16(Ag0 + k0, As + e0);
    gl_lds16(Ag1 + k0, As + e1);
    gl_lds16(Bg0 + k0, Bs + e0);
    gl_lds16(Bg1 + k0, Bs + e1);
    __syncthreads();
    short8v af[4], bfv[4];
    #pragma unroll
    for (int m=0;m<4;m++) af[m]  = *(const short8v*)(As + aoff[m]);
    #pragma unroll
    for (int n=0;n<4;n++) bfv[n] = *(const short8v*)(Bs + boff[n]);
    #pragma unroll
    for (int m=0;m<4;m++)
      #pragma unroll
      for (int n=0;n<4;n++)
        acc[m][n] = __builtin_amdgcn_mfma_f32_16x16x32_bf16(af[m], bfv[n], acc[m][n], 0, 0, 0);
    __syncthreads();
  }

  #pragma unroll
  for (int m=0;m<4;m++){
    const int rowb = bm + wr + m*16 + (lane>>4)*4;
    #pragma unroll
    for (int n=0;n<4;n++){
      const int col = bn + wc + n*16 + (lane&15);
      #pragma unroll
      for (int r=0;r<4;r++){
        const int row = rowb + r;
        if (SK == 1) Out[(size_t)row*N + col] = acc[m][n][r];
        else         Part[(size_t)blockIdx.z*M*N + (size_t)row*N + col] = acc[m][n][r];
      }
    }
  }
}

// ---------------- f32 GEMM (small shapes): C[r,c]=sum_k A[r*lda+k]*B[c*ldb+k] ----------------
template<int EPI>
__global__ void gemm64(const float* __restrict__ A, int lda,
                       const float* __restrict__ Bw, int ldb,
                       float* __restrict__ Out, float* __restrict__ Part,
                       const float* __restrict__ aux,
                       int M, int N, int K, int SK)
{
  __shared__ float As[16][64], Bs[16][64];
  const int tid = threadIdx.x;
  const int bm = blockIdx.y*64, bn = blockIdx.x*64;
  const int kc = K/SK, kBeg = blockIdx.z*kc, kEnd = kBeg + kc;
  const int lr = tid>>2, lk = (tid&3)<<2;
  const int tx = tid&15, ty = tid>>4;
  float acc[4][4];
  #pragma unroll
  for (int i=0;i<4;i++)
    #pragma unroll
    for (int j=0;j<4;j++) acc[i][j] = 0.f;
  const float* Ap = A + (size_t)(bm+lr)*lda + lk;
  const bool bok = (bn+lr) < N;
  const float* Bp = Bw + (size_t)(bn+lr)*ldb + lk;
  for (int k0=kBeg; k0<kEnd; k0+=16){
    float4 a0 = *(const float4*)(Ap + k0);
    float4 b0 = {0,0,0,0};
    if (bok) b0 = *(const float4*)(Bp + k0);
    __syncthreads();
    As[lk+0][lr]=a0.x; As[lk+1][lr]=a0.y; As[lk+2][lr]=a0.z; As[lk+3][lr]=a0.w;
    Bs[lk+0][lr]=b0.x; Bs[lk+1][lr]=b0.y; Bs[lk+2][lr]=b0.z; Bs[lk+3][lr]=b0.w;
    __syncthreads();
    #pragma unroll
    for (int kk=0;kk<16;kk++){
      float a[4], b[4];
      *(float4*)a = *(const float4*)&As[kk][ty*4];
      *(float4*)b = *(const float4*)&Bs[kk][tx*4];
      #pragma unroll
      for (int i=0;i<4;i++)
        #pragma unroll
        for (int j=0;j<4;j++) acc[i][j] = fmaf(a[i], b[j], acc[i][j]);
    }
  }
  #pragma unroll
  for (int i=0;i<4;i++){
    const int row = bm + ty*4 + i;
    #pragma unroll
    for (int j=0;j<4;j++){
      const int col = bn + tx*4 + j;
      if (col < N){
        if (SK == 1){
          float vv = acc[i][j];
          if (EPI==1){ vv += aux[col]; vv = fmaxf(vv,0.f) + log1pf(__expf(-fabsf(vv))); }
          Out[(size_t)row*N+col] = vv;
        } else {
          Part[(size_t)blockIdx.z*M*N + (size_t)row*N+col] = acc[i][j];
        }
      }
    }
  }
}

// EPI: 0 plain sum, 2 sum + aux[i] (residual)
template<int EPI>
__global__ void reduce_k(const float* __restrict__ Part, float* __restrict__ Out,
                         const float* __restrict__ aux, int MN, int SK)
{
  const int i = blockIdx.x*256 + threadIdx.x;
  if (i >= MN) return;
  float s = 0.f;
  for (int z=0; z<SK; z++) s += Part[(size_t)z*MN + i];
  if (EPI==2) s += aux[i];
  Out[i] = s;
}

// ---------------- causal depthwise conv (width 4) + bias + silu ----------------
__global__ void conv_k(const float* __restrict__ xz, const float* __restrict__ cw,
                       const float* __restrict__ cb, float* __restrict__ xc)
{
  const int d = blockIdx.x*256 + threadIdx.x;
  const int g = blockIdx.y;
  const int b = g >> 9, t = g & (SEQL-1);
  float4 w4 = *(const float4*)(cw + (size_t)d*4);
  const float wk[4] = {w4.x, w4.y, w4.z, w4.w};
  const float* col = xz + ((size_t)b*SEQL)*(2*DI) + d;
  float acc = cb[d];
  #pragma unroll
  for (int k=0;k<4;k++){
    int tt = t - 3 + k;
    if (tt >= 0) acc = fmaf(wk[k], col[(size_t)tt*(2*DI)], acc);
  }
  xc[(size_t)g*DI + d] = silu_(acc);
}

// ---------------- pass 1: per-chunk v aggregates + dt prefix sums ----------------
__global__ void vagg_k(const float* __restrict__ dt, const float* __restrict__ xcp,
                       const float* __restrict__ xdbl, float* __restrict__ Vagg,
                       float* __restrict__ S, float* __restrict__ cumdt)
{
  const int d = blockIdx.x*256 + threadIdx.x;
  const int c = blockIdx.y, b = blockIdx.z;
  float acc[16];
  #pragma unroll
  for (int n=0;n<16;n++) acc[n] = 0.f;
  float sdt = 0.f;
  for (int s=0;s<TT;s++){
    const int g = b*SEQL + c*TT + s;
    float dv = dt[(size_t)g*DI + d];
    float w  = dv * xcp[(size_t)g*DI + d];
    sdt += dv;
    cumdt[(size_t)g*DI + d] = sdt;      // inclusive prefix within chunk
    #pragma unroll
    for (int n=0;n<16;n++) acc[n] = fmaf(BETA, acc[n], w * xdbl[(size_t)g*XDC + 48 + n]);
  }
  const size_t base = ((size_t)(b*CC + c)*NDS)*DI + d;
  #pragma unroll
  for (int n=0;n<16;n++) Vagg[base + (size_t)n*DI] = acc[n];
  S[(size_t)(b*CC + c)*DI + d] = sdt;
}

// ---------------- pass 2: sequential-over-chunks combine for v_start ----------------
__global__ void vcomb_k(const float* __restrict__ Vagg, float* __restrict__ vst, float betaT)
{
  const int d = blockIdx.x*256 + threadIdx.x;
  const int n = blockIdx.y, b = blockIdx.z;
  const size_t stride = (size_t)NDS*DI;
  size_t idx = ((size_t)(b*CC)*NDS + n)*DI + d;
  float v = 0.f;
  for (int c=0;c<CC;c++){
    vst[idx] = v;
    v = fmaf(betaT, v, Vagg[idx]);
    idx += stride;
  }
}

// ---------------- gram_k: LDS-tiled 24x24 Gram of X=[v0|W] + full NS -> Q matrices ----
// M = X^T X: R0 = M[0:16,0:16], P0[n][s] = M[n][16+s], G[r][s] = M[16+r][16+s]
// R_t recurrence via closed-form p_t; Q_t = (aI + b R/nu^2 + c R^2/nu^4)/nu
__global__ __launch_bounds__(256) void gram_k(
    const float* __restrict__ vst, const float* __restrict__ dt,
    const float* __restrict__ xcp, const float* __restrict__ xdbl,
    float* __restrict__ Qg)
{
  const int c = blockIdx.x, b = blockIdx.y;
  const int tid = threadIdx.x;
  __shared__ float Xs[64][25];
  __shared__ float Ms[24][25];
  __shared__ float sB[8][16];
  __shared__ float Rm[16][17];

  const size_t vbase = ((size_t)(b*CC + c)*NDS)*DI;
  const size_t gbase = (size_t)(b*SEQL + c*TT);

  // 576 outputs over 256 threads: o = tid, tid+256, (tid<64: tid+512)
  const int i0 = tid/24,        j0 = tid%24;
  const int i1 = (tid+256)/24,  j1 = (tid+256)%24;
  const int i2 = (tid+512)/24,  j2 = (tid+512)%24;
  float a0 = 0.f, a1 = 0.f, a2 = 0.f;

  for (int k0 = 0; k0 < DI; k0 += 64){
    __syncthreads();
    #pragma unroll
    for (int q = 0; q < 6; q++){
      const int p = tid + q*256;
      const int row = p & 63, col = p >> 6;
      float xv;
      if (col < 16){
        xv = vst[vbase + (size_t)col*DI + k0 + row];
      } else {
        const size_t ii = (gbase + (col-16))*DI + k0 + row;
        xv = dt[ii]*xcp[ii];
      }
      Xs[row][col] = xv;
    }
    __syncthreads();
    #pragma unroll 16
    for (int k = 0; k < 64; k++){
      a0 = fmaf(Xs[k][i0], Xs[k][j0], a0);
      a1 = fmaf(Xs[k][i1], Xs[k][j1], a1);
      if (tid < 64) a2 = fmaf(Xs[k][i2], Xs[k][j2], a2);
    }
  }
  __syncthreads();
  Ms[i0][j0] = a0;
  Ms[i1][j1] = a1;
  if (tid < 64) Ms[i2][j2] = a2;
  if (tid < 128){ const int s = tid>>4, n = tid&15; sB[s][n] = xdbl[(gbase + s)*XDC + 48 + n]; }
  __syncthreads();

  // NS phase: 256 threads = full 16x16 (i,j); R in register, recurrence over t
  const int i = tid >> 4, j = tid & 15;
  float Rreg = Ms[i][j];
  constexpr float PB[9] = {1.f, 0.9f, 0.81f, 0.729f, 0.6561f, 0.59049f,
                           0.531441f, 0.4782969f, 0.43046721f};
  const size_t qbase = ((size_t)(b*CC + c)*TT)*256;
  #pragma unroll
  for (int t=0;t<TT;t++){
    float p_i = PB[t]*Ms[i][16+t];
    float p_j = PB[t]*Ms[j][16+t];
    #pragma unroll
    for (int r=0;r<t;r++){
      const float gg = Ms[16+r][16+t];
      p_i = fmaf(PB[t-1-r]*gg, sB[r][i], p_i);
      p_j = fmaf(PB[t-1-r]*gg, sB[r][j], p_j);
    }
    const float bi = sB[t][i], bj = sB[t][j];
    const float gtt = Ms[16+t][16+t];
    Rreg = BETA*BETA*Rreg + BETA*(p_i*bj + bi*p_j) + gtt*bi*bj;
    Rm[i][j] = Rreg;
    __syncthreads();
    float tr = 0.f;
    #pragma unroll
    for (int k=0;k<16;k++) tr += Rm[k][k];
    const float nu = sqrtf(tr) + 1e-7f;
    const float inv_nu = 1.f/nu;
    const float inv2 = inv_nu*inv_nu;
    const float inv4 = inv2*inv2;
    float a2v = 0.f;
    #pragma unroll
    for (int k=0;k<16;k++) a2v = fmaf(Rm[i][k], Rm[k][j], a2v);
    float q = NSB*inv2*Rreg + NSC*inv4*a2v;
    if (i == j) q += NSA;
    Qg[qbase + t*256 + tid] = q * inv_nu;
    __syncthreads();
  }
}

// ---------------- apply_k: barrier-free in-chunk scan, 1 d-row per thread ----------------
__global__ __launch_bounds__(256) void apply_k(
    const float* __restrict__ vst, const float* __restrict__ dt,
    const float* __restrict__ xcp, const float* __restrict__ xdbl,
    const float* __restrict__ Qg, const float* __restrict__ A_log,
    float* __restrict__ ylocal, float* __restrict__ hend)
{
  const int c = blockIdx.x, b = blockIdx.y, z = blockIdx.z;
  const int tid = threadIdx.x;
  const int d = z*256 + tid;
  __shared__ float sQ[8*256];
  __shared__ float sBC[8][32];

  const size_t qbase = ((size_t)(b*CC + c)*TT)*256;
  #pragma unroll
  for (int q=0;q<8;q++) sQ[q*256 + tid] = Qg[qbase + q*256 + tid];
  {
    const int s = tid >> 5, idx = tid & 31;
    sBC[s][idx] = xdbl[(size_t)(b*SEQL + c*TT + s)*XDC + 48 + idx];
  }
  __syncthreads();

  float v[16], h[16], Ar[16];
  {
    const float* vs = vst + ((size_t)(b*CC + c)*NDS)*DI + d;
    const float* arow = A_log + (size_t)d*NDS;
    #pragma unroll
    for (int n=0;n<16;n++){
      v[n] = vs[(size_t)n*DI];
      h[n] = 0.f;
      Ar[n] = -__expf(arow[n]) * LOG2E;
    }
  }

  for (int t=0;t<TT;t++){
    const size_t g = (size_t)(b*SEQL + c*TT + t);
    const float dtv = dt[g*DI + d];
    const float wv  = dtv * xcp[g*DI + d];
    #pragma unroll
    for (int n=0;n<16;n++) v[n] = fmaf(BETA, v[n], wv*sBC[t][n]);
    float un[16];
    #pragma unroll
    for (int n=0;n<16;n++) un[n] = 0.f;
    const float* qt = sQ + t*256;
    #pragma unroll
    for (int k=0;k<16;k++){
      const float vk = v[k];
      const float4 q0 = *(const float4*)(qt + k*16);
      const float4 q1 = *(const float4*)(qt + k*16 + 4);
      const float4 q2 = *(const float4*)(qt + k*16 + 8);
      const float4 q3 = *(const float4*)(qt + k*16 + 12);
      un[0]=fmaf(vk,q0.x,un[0]); un[1]=fmaf(vk,q0.y,un[1]); un[2]=fmaf(vk,q0.z,un[2]); un[3]=fmaf(vk,q0.w,un[3]);
      un[4]=fmaf(vk,q1.x,un[4]); un[5]=fmaf(vk,q1.y,un[5]); un[6]=fmaf(vk,q1.z,un[6]); un[7]=fmaf(vk,q1.w,un[7]);
      un[8]=fmaf(vk,q2.x,un[8]); un[9]=fmaf(vk,q2.y,un[9]); un[10]=fmaf(vk,q2.z,un[10]); un[11]=fmaf(vk,q2.w,un[11]);
      un[12]=fmaf(vk,q3.x,un[12]); un[13]=fmaf(vk,q3.y,un[13]); un[14]=fmaf(vk,q3.z,un[14]); un[15]=fmaf(vk,q3.w,un[15]);
    }
    float y = 0.f;
    #pragma unroll
    for (int n=0;n<16;n++){
      const float e = exp2f(dtv*Ar[n]);
      h[n] = fmaf(e, h[n], un[n]);
      y = fmaf(h[n], sBC[t][16+n], y);
    }
    ylocal[g*DI + d] = y;
  }
  float* he = hend + ((size_t)(b*CC + c)*NDS)*DI + d;
  #pragma unroll
  for (int n=0;n<16;n++) he[(size_t)n*DI] = h[n];
}

// ---------------- pass 4: combine h chunk-starts ----------------
__global__ void hcomb_k(const float* __restrict__ hend, const float* __restrict__ S,
                        const float* __restrict__ A_log, float* __restrict__ hst)
{
  const int d = blockIdx.x*256 + threadIdx.x;
  const int n = blockIdx.y, b = blockIdx.z;
  const float An = -__expf(A_log[(size_t)d*NDS + n]);
  const size_t stride = (size_t)NDS*DI;
  size_t idx  = ((size_t)(b*CC)*NDS + n)*DI + d;
  size_t sidx = (size_t)(b*CC)*DI + d;
  float hv = 0.f;
  for (int c=0;c<CC;c++){
    hst[idx] = hv;
    hv = fmaf(__expf(An * S[sidx]), hv, hend[idx]);
    idx += stride; sidx += DI;
  }
}

// ---------------- pass 5: y epilogue -> bf16 gated output ----------------
__global__ void yepi_k(const float* __restrict__ ylocal, const float* __restrict__ hst,
                       const float* __restrict__ cumdt, const float* __restrict__ xdbl,
                       const float* __restrict__ A_log, const float* __restrict__ Dv,
                       const float* __restrict__ xcp, const float* __restrict__ xz,
                       unsigned short* __restrict__ ybf)
{
  const int d = blockIdx.x*256 + threadIdx.x;
  const int g = blockIdx.y;
  const int b = g >> 9, t = g & (SEQL-1);
  const int c = t / TT;
  const float ddt = cumdt[(size_t)g*DI + d];
  const float* hs = hst + ((size_t)(b*CC + c)*NDS)*DI + d;
  const float* ar = A_log + (size_t)d*NDS;
  float corr = 0.f;
  #pragma unroll
  for (int n=0;n<16;n++){
    float An = -__expf(ar[n]);
    float Cn = xdbl[(size_t)g*XDC + 64 + n];
    corr = fmaf(hs[(size_t)n*DI] * __expf(An*ddt), Cn, corr);
  }
  float y = ylocal[(size_t)g*DI + d] + corr + Dv[d]*xcp[(size_t)g*DI + d];
  float z = xz[(size_t)g*(2*DI) + DI + d];
  ybf[(size_t)g*DI + d] = bfr(y * silu_(z));
}

// ============================== host ==============================
extern "C" void kernel_launch(void* const* d_in, const int* in_sizes, int n_in,
                              void* d_out, int out_size, void* d_ws, size_t ws_size,
                              hipStream_t stream)
{
  (void)in_sizes; (void)n_in; (void)out_size; (void)ws_size;
  const float* x      = (const float*)d_in[0];
  const float* in_w   = (const float*)d_in[1];
  const float* conv_w = (const float*)d_in[2];
  const float* conv_b = (const float*)d_in[3];
  const float* xp_w   = (const float*)d_in[4];
  const float* dtp_w  = (const float*)d_in[5];
  const float* dtp_b  = (const float*)d_in[6];
  const float* A_log  = (const float*)d_in[7];
  const float* Dp     = (const float*)d_in[8];
  const float* out_w  = (const float*)d_in[9];
  const float* norm_w = (const float*)d_in[10];
  const float* fnorm  = (const float*)d_in[11];

  const float betaT = powf(BETA, (float)TT);
  const int skx = 8, skout = 4;

  float* w0 = (float*)d_ws; size_t off = 0;
  auto alloc = [&](size_t n)->float*{ float* p = w0 + off; off += (n + 63) & ~(size_t)63; return p; };
  float* xa     = alloc((size_t)NT*DM);
  float* xb     = alloc((size_t)NT*DM);
  float* bfA    = alloc((size_t)NT*DI/2);       // bf16 A-matrices (xnb then ybf)
  float* xz     = alloc((size_t)NT*2*DI);
  float* xcb    = alloc((size_t)NT*DI);
  float* xdbl   = alloc((size_t)NT*XDC);
  float* dtb    = alloc((size_t)NT*DI);
  float* cumdt  = alloc((size_t)NT*DI);
  float* ylocal = alloc((size_t)NT*DI);
  float* Sbuf   = alloc((size_t)NB*CC*DI);
  float* Qg     = alloc((size_t)NB*CC*TT*256);
  float* big1   = alloc((size_t)NB*CC*NDS*DI);  // x_proj partials / Vagg / hend / out_proj partials
  float* big2   = alloc((size_t)NB*CC*NDS*DI);  // wbf / vst / hst / wbf(out)

  unsigned short* xnb = (unsigned short*)bfA;   // [NT][DM]
  unsigned short* ybf = (unsigned short*)bfA;   // [NT][DI]
  unsigned short* wbf = (unsigned short*)big2;  // bf16 weights (lifetimes disjoint from vst/hst)
  float* partb = big1;

  const float* xcur = x;
  float* nxt = xa;
  for (int l=0; l<2; l++){
    const float* inw_l = in_w   + (size_t)l*2*DI*DM;
    const float* cw_l  = conv_w + (size_t)l*DI*4;
    const float* cb_l  = conv_b + (size_t)l*DI;
    const float* xpw_l = xp_w   + (size_t)l*XDC*DI;
    const float* dtw_l = dtp_w  + (size_t)l*DI*DTR;
    const float* dtbi  = dtp_b  + (size_t)l*DI;
    const float* al_l  = A_log  + (size_t)l*DI*NDS;
    const float* d_l   = Dp     + (size_t)l*DI;
    const float* ow_l  = out_w  + (size_t)l*DM*DI;
    const float* nw_l  = norm_w + (size_t)l*DM;

    castbf_k<<<dim3((2*DI*DM/4+255)/256), dim3(256), 0, stream>>>(inw_l, wbf, 2*DI*DM/4);
    rms_k<1><<<dim3(NT), dim3(256), 0, stream>>>(xcur, nw_l, xnb);
    gemm_mf<0><<<dim3(2*DI/128, NT/128, 1), dim3(256), 0, stream>>>(
        xnb, DM, wbf, DM, xz, nullptr, NT, 2*DI, DM, 1);
    conv_k<<<dim3(DI/256, NT), dim3(256), 0, stream>>>(xz, cw_l, cb_l, xcb);
    gemm64<0><<<dim3((XDC+63)/64, NT/64, skx), dim3(256), 0, stream>>>(
        xcb, DI, xpw_l, DI, xdbl, partb, nullptr, NT, XDC, DI, skx);
    reduce_k<0><<<dim3((NT*XDC+255)/256), dim3(256), 0, stream>>>(partb, xdbl, nullptr, NT*XDC, skx);
    gemm64<1><<<dim3(DI/64, NT/64, 1), dim3(256), 0, stream>>>(
        xdbl, XDC, dtw_l, DTR, dtb, partb, dtbi, NT, DI, DTR, 1);
    vagg_k<<<dim3(DI/256, CC, NB), dim3(256), 0, stream>>>(dtb, xcb, xdbl, big1, Sbuf, cumdt);
    vcomb_k<<<dim3(DI/256, NDS, NB), dim3(256), 0, stream>>>(big1, big2, betaT);
    gram_k<<<dim3(CC, NB), dim3(256), 0, stream>>>(big2, dtb, xcb, xdbl, Qg);
    apply_k<<<dim3(CC, NB, DI/256), dim3(256), 0, stream>>>(
        big2, dtb, xcb, xdbl, Qg, al_l, ylocal, big1);
    hcomb_k<<<dim3(DI/256, NDS, NB), dim3(256), 0, stream>>>(big1, Sbuf, al_l, big2);
    yepi_k<<<dim3(DI/256, NT), dim3(256), 0, stream>>>(ylocal, big2, cumdt, xdbl, al_l, d_l, xcb, xz, ybf);
    castbf_k<<<dim3((DM*DI/4+255)/256), dim3(256), 0, stream>>>(ow_l, wbf, DM*DI/4);
    gemm_mf<0><<<dim3(DM/128, NT/128, skout), dim3(256), 0, stream>>>(
        ybf, DI, wbf, DI, nxt, partb, NT, DM, DI, skout);
    reduce_k<2><<<dim3((NT*DM+255)/256), dim3(256), 0, stream>>>(partb, nxt, xcur, NT*DM, skout);
    xcur = nxt; nxt = xb;
  }
  rms_k<0><<<dim3(NT), dim3(256), 0, stream>>>(xcur, fnorm, (float*)d_out);
}

// Round 8
// 448.564 us; speedup vs baseline: 1.4112x; 1.4112x over previous
//
#include <hip/hip_runtime.h>
#include <math.h>

#define DM   768
#define DI   1536
#define NDS  16
#define DTR  48
#define XDC  80
#define NB   2
#define SEQL 512
#define NT   (NB*SEQL)
#define CC   64
#define TT   8
#define BETA 0.9f
#define NSA  3.4445f
#define NSB  (-4.775f)
#define NSC  2.0315f
#define LOG2E 1.4426950408889634f
#define GKH  768
#define GKS  772   // Xs row stride (floats); 772*4=3088 bytes, 16B-aligned

typedef __attribute__((ext_vector_type(8))) short short8v;
typedef __attribute__((ext_vector_type(4))) float f32x4;

__device__ __forceinline__ float silu_(float x){ return x / (1.f + __expf(-x)); }
__device__ __forceinline__ unsigned short bfr(float x){
  unsigned u = __float_as_uint(x);
  return (unsigned short)((u + 0x7fffu + ((u>>16)&1u)) >> 16);
}
__device__ __forceinline__ void gl_lds16(const unsigned short* g, unsigned short* l){
  __builtin_amdgcn_global_load_lds((const __attribute__((address_space(1))) void*)g,
                                   (__attribute__((address_space(3))) void*)l, 16, 0, 0);
}

// ---------------- rmsnorm: one block per token; BF=1 -> bf16 output ----------------
template<int BF>
__global__ void rms_k(const float* __restrict__ X, const float* __restrict__ W,
                      void* __restrict__ Ov)
{
  const int g = blockIdx.x, tid = threadIdx.x;
  const float* xr = X + (size_t)g*DM;
  float x0 = xr[tid], x1 = xr[tid+256], x2 = xr[tid+512];
  float ss = x0*x0 + x1*x1 + x2*x2;
  #pragma unroll
  for (int m=1; m<=32; m<<=1) ss += __shfl_xor(ss, m);
  __shared__ float ws[4];
  if ((tid & 63) == 0) ws[tid>>6] = ss;
  __syncthreads();
  float sc = rsqrtf((ws[0]+ws[1]+ws[2]+ws[3])*(1.f/DM) + 1e-5f);
  if (BF){
    unsigned short* o = (unsigned short*)Ov + (size_t)g*DM;
    o[tid]     = bfr(x0*sc*W[tid]);
    o[tid+256] = bfr(x1*sc*W[tid+256]);
    o[tid+512] = bfr(x2*sc*W[tid+512]);
  } else {
    float* o = (float*)Ov + (size_t)g*DM;
    o[tid]     = x0*sc*W[tid];
    o[tid+256] = x1*sc*W[tid+256];
    o[tid+512] = x2*sc*W[tid+512];
  }
}

// ---------------- f32 -> bf16 cast (vectorized) ----------------
__global__ void castbf_k(const float* __restrict__ in, unsigned short* __restrict__ out, int n4)
{
  const int i = blockIdx.x*256 + threadIdx.x;
  if (i >= n4) return;
  float4 v = ((const float4*)in)[i];
  ushort4 o;
  o.x = bfr(v.x); o.y = bfr(v.y); o.z = bfr(v.z); o.w = bfr(v.w);
  ((ushort4*)out)[i] = o;
}

// ---------------- bf16 MFMA GEMM (m97 structure): C = A * B^T ----------------
template<int EPI>
__global__ __launch_bounds__(256) void gemm_mf(
    const unsigned short* __restrict__ Abf, int lda,
    const unsigned short* __restrict__ Bbf, int ldb,
    float* __restrict__ Out, float* __restrict__ Part,
    int M, int N, int K, int SK)
{
  __shared__ unsigned short As[128*32];
  __shared__ unsigned short Bs[128*32];
  const int tid  = threadIdx.x;
  const int wid  = tid >> 6, lane = tid & 63;
  const int bm   = blockIdx.y*128, bn = blockIdx.x*128;
  const int kc   = K/SK, kBeg = blockIdx.z*kc, kEnd = kBeg + kc;
  const int wr   = (wid>>1)*64, wc = (wid&1)*64;

  f32x4 acc[4][4];
  #pragma unroll
  for (int m=0;m<4;m++)
    #pragma unroll
    for (int n=0;n<4;n++) acc[m][n] = (f32x4){0.f,0.f,0.f,0.f};

  const int e0 = (wid*2)*512 + lane*8;
  const int e1 = e0 + 512;
  const int r0 = e0 >> 5, k0e = e0 & 31;
  const int r1 = e1 >> 5, k1e = e1 & 31;
  const unsigned short* Ag0 = Abf + (size_t)(bm + r0)*lda + k0e;
  const unsigned short* Ag1 = Abf + (size_t)(bm + r1)*lda + k1e;
  const unsigned short* Bg0 = Bbf + (size_t)(bn + r0)*ldb + k0e;
  const unsigned short* Bg1 = Bbf + (size_t)(bn + r1)*ldb + k1e;

  int aoff[4], boff[4];
  #pragma unroll
  for (int m=0;m<4;m++) aoff[m] = (wr + m*16 + (lane&15))*32 + (lane>>4)*8;
  #pragma unroll
  for (int n=0;n<4;n++) boff[n] = (wc + n*16 + (lane&15))*32 + (lane>>4)*8;

  for (int k0 = kBeg; k0 < kEnd; k0 += 32){
    gl_lds16(Ag0 + k0, As + e0);
    gl_lds16(Ag1 + k0, As + e1);
    gl_lds16(Bg0 + k0, Bs + e0);
    gl_lds16(Bg1 + k0, Bs + e1);
    __syncthreads();
    short8v af[4], bfv[4];
    #pragma unroll
    for (int m=0;m<4;m++) af[m]  = *(const short8v*)(As + aoff[m]);
    #pragma unroll
    for (int n=0;n<4;n++) bfv[n] = *(const short8v*)(Bs + boff[n]);
    #pragma unroll
    for (int m=0;m<4;m++)
      #pragma unroll
      for (int n=0;n<4;n++)
        acc[m][n] = __builtin_amdgcn_mfma_f32_16x16x32_bf16(af[m], bfv[n], acc[m][n], 0, 0, 0);
    __syncthreads();
  }

  #pragma unroll
  for (int m=0;m<4;m++){
    const int rowb = bm + wr + m*16 + (lane>>4)*4;
    #pragma unroll
    for (int n=0;n<4;n++){
      const int col = bn + wc + n*16 + (lane&15);
      #pragma unroll
      for (int r=0;r<4;r++){
        const int row = rowb + r;
        if (SK == 1) Out[(size_t)row*N + col] = acc[m][n][r];
        else         Part[(size_t)blockIdx.z*M*N + (size_t)row*N + col] = acc[m][n][r];
      }
    }
  }
}

// ---------------- f32 GEMM (small shapes): C[r,c]=sum_k A[r*lda+k]*B[c*ldb+k] ----------------
template<int EPI>
__global__ void gemm64(const float* __restrict__ A, int lda,
                       const float* __restrict__ Bw, int ldb,
                       float* __restrict__ Out, float* __restrict__ Part,
                       const float* __restrict__ aux,
                       int M, int N, int K, int SK)
{
  __shared__ float As[16][64], Bs[16][64];
  const int tid = threadIdx.x;
  const int bm = blockIdx.y*64, bn = blockIdx.x*64;
  const int kc = K/SK, kBeg = blockIdx.z*kc, kEnd = kBeg + kc;
  const int lr = tid>>2, lk = (tid&3)<<2;
  const int tx = tid&15, ty = tid>>4;
  float acc[4][4];
  #pragma unroll
  for (int i=0;i<4;i++)
    #pragma unroll
    for (int j=0;j<4;j++) acc[i][j] = 0.f;
  const float* Ap = A + (size_t)(bm+lr)*lda + lk;
  const bool bok = (bn+lr) < N;
  const float* Bp = Bw + (size_t)(bn+lr)*ldb + lk;
  for (int k0=kBeg; k0<kEnd; k0+=16){
    float4 a0 = *(const float4*)(Ap + k0);
    float4 b0 = {0,0,0,0};
    if (bok) b0 = *(const float4*)(Bp + k0);
    __syncthreads();
    As[lk+0][lr]=a0.x; As[lk+1][lr]=a0.y; As[lk+2][lr]=a0.z; As[lk+3][lr]=a0.w;
    Bs[lk+0][lr]=b0.x; Bs[lk+1][lr]=b0.y; Bs[lk+2][lr]=b0.z; Bs[lk+3][lr]=b0.w;
    __syncthreads();
    #pragma unroll
    for (int kk=0;kk<16;kk++){
      float a[4], b[4];
      *(float4*)a = *(const float4*)&As[kk][ty*4];
      *(float4*)b = *(const float4*)&Bs[kk][tx*4];
      #pragma unroll
      for (int i=0;i<4;i++)
        #pragma unroll
        for (int j=0;j<4;j++) acc[i][j] = fmaf(a[i], b[j], acc[i][j]);
    }
  }
  #pragma unroll
  for (int i=0;i<4;i++){
    const int row = bm + ty*4 + i;
    #pragma unroll
    for (int j=0;j<4;j++){
      const int col = bn + tx*4 + j;
      if (col < N){
        if (SK == 1){
          float vv = acc[i][j];
          if (EPI==1){ vv += aux[col]; vv = fmaxf(vv,0.f) + log1pf(__expf(-fabsf(vv))); }
          Out[(size_t)row*N+col] = vv;
        } else {
          Part[(size_t)blockIdx.z*M*N + (size_t)row*N+col] = acc[i][j];
        }
      }
    }
  }
}

// EPI: 0 plain sum, 2 sum + aux[i] (residual)
template<int EPI>
__global__ void reduce_k(const float* __restrict__ Part, float* __restrict__ Out,
                         const float* __restrict__ aux, int MN, int SK)
{
  const int i = blockIdx.x*256 + threadIdx.x;
  if (i >= MN) return;
  float s = 0.f;
  for (int z=0; z<SK; z++) s += Part[(size_t)z*MN + i];
  if (EPI==2) s += aux[i];
  Out[i] = s;
}

// ---------------- causal depthwise conv (width 4) + bias + silu ----------------
__global__ void conv_k(const float* __restrict__ xz, const float* __restrict__ cw,
                       const float* __restrict__ cb, float* __restrict__ xc)
{
  const int d = blockIdx.x*256 + threadIdx.x;
  const int g = blockIdx.y;
  const int b = g >> 9, t = g & (SEQL-1);
  float4 w4 = *(const float4*)(cw + (size_t)d*4);
  const float wk[4] = {w4.x, w4.y, w4.z, w4.w};
  const float* col = xz + ((size_t)b*SEQL)*(2*DI) + d;
  float acc = cb[d];
  #pragma unroll
  for (int k=0;k<4;k++){
    int tt = t - 3 + k;
    if (tt >= 0) acc = fmaf(wk[k], col[(size_t)tt*(2*DI)], acc);
  }
  xc[(size_t)g*DI + d] = silu_(acc);
}

// ---------------- pass 1: per-chunk v aggregates + dt prefix sums ----------------
__global__ void vagg_k(const float* __restrict__ dt, const float* __restrict__ xcp,
                       const float* __restrict__ xdbl, float* __restrict__ Vagg,
                       float* __restrict__ S, float* __restrict__ cumdt)
{
  const int d = blockIdx.x*256 + threadIdx.x;
  const int c = blockIdx.y, b = blockIdx.z;
  float acc[16];
  #pragma unroll
  for (int n=0;n<16;n++) acc[n] = 0.f;
  float sdt = 0.f;
  for (int s=0;s<TT;s++){
    const int g = b*SEQL + c*TT + s;
    float dv = dt[(size_t)g*DI + d];
    float w  = dv * xcp[(size_t)g*DI + d];
    sdt += dv;
    cumdt[(size_t)g*DI + d] = sdt;      // inclusive prefix within chunk
    #pragma unroll
    for (int n=0;n<16;n++) acc[n] = fmaf(BETA, acc[n], w * xdbl[(size_t)g*XDC + 48 + n]);
  }
  const size_t base = ((size_t)(b*CC + c)*NDS)*DI + d;
  #pragma unroll
  for (int n=0;n<16;n++) Vagg[base + (size_t)n*DI] = acc[n];
  S[(size_t)(b*CC + c)*DI + d] = sdt;
}

// ---------------- pass 2: sequential-over-chunks combine for v_start ----------------
__global__ void vcomb_k(const float* __restrict__ Vagg, float* __restrict__ vst, float betaT)
{
  const int d = blockIdx.x*256 + threadIdx.x;
  const int n = blockIdx.y, b = blockIdx.z;
  const size_t stride = (size_t)NDS*DI;
  size_t idx = ((size_t)(b*CC)*NDS + n)*DI + d;
  float v = 0.f;
  for (int c=0;c<CC;c++){
    vst[idx] = v;
    v = fmaf(betaT, v, Vagg[idx]);
    idx += stride;
  }
}

// ---------------- gram_k: register-tiled 24x24 Gram of X=[v0|W] + full NS -> Q ----------
// LDS slab Xs[col][k] k-contiguous (2 passes of 768 k). 21 upper-tri 4x4 tiles x 12 k-segs.
// b128 LDS reads: 8 reads -> 64 FMA per k4 step. Partials reduced via dead Xs space.
__global__ __launch_bounds__(256) void gram_k(
    const float* __restrict__ vst, const float* __restrict__ dt,
    const float* __restrict__ xcp, const float* __restrict__ xdbl,
    float* __restrict__ Qg)
{
  const int c = blockIdx.x, b = blockIdx.y;
  const int tid = threadIdx.x;
  __shared__ float Xs[24*GKS];     // 74.1 KB
  __shared__ float Ms[24][25];
  __shared__ float sB[8][16];
  __shared__ float Rm[16][17];

  const size_t vbase = ((size_t)(b*CC + c)*NDS)*DI;
  const size_t gbase = (size_t)(b*SEQL + c*TT);

  const bool active = tid < 252;
  const int tile = tid / 12, seg = tid % 12;
  int ti = 0, tj = 0;
  {
    int tt = tile;
    if (active){ while (tt >= 6 - ti){ tt -= 6 - ti; ti++; } tj = ti + tt; }
  }
  const int i0 = ti*4, j0 = tj*4;
  const int ks = seg*64;
  float acc[4][4];
  #pragma unroll
  for (int i=0;i<4;i++)
    #pragma unroll
    for (int j=0;j<4;j++) acc[i][j] = 0.f;

  for (int pass = 0; pass < 2; pass++){
    const int koff = pass * GKH;
    __syncthreads();
    #pragma unroll
    for (int q = 0; q < 18; q++){
      const int p = tid + q*256;
      const int col = p / 192;            // 192 float4 per column
      const int kk  = (p % 192) * 4;
      float4 xv;
      if (col < 16){
        xv = *(const float4*)(vst + vbase + (size_t)col*DI + koff + kk);
      } else {
        const size_t ii = (gbase + (col-16))*DI + koff + kk;
        float4 dv = *(const float4*)(dt + ii);
        float4 xc = *(const float4*)(xcp + ii);
        xv.x = dv.x*xc.x; xv.y = dv.y*xc.y; xv.z = dv.z*xc.z; xv.w = dv.w*xc.w;
      }
      *(float4*)(Xs + col*GKS + kk) = xv;
    }
    __syncthreads();
    if (active){
      for (int k4 = 0; k4 < 64; k4 += 4){
        float4 av[4], bv[4];
        #pragma unroll
        for (int r=0;r<4;r++) av[r] = *(const float4*)(Xs + (i0+r)*GKS + ks + k4);
        #pragma unroll
        for (int r=0;r<4;r++) bv[r] = *(const float4*)(Xs + (j0+r)*GKS + ks + k4);
        #pragma unroll
        for (int i=0;i<4;i++)
          #pragma unroll
          for (int j=0;j<4;j++){
            float s = fmaf(av[i].x, bv[j].x, acc[i][j]);
            s = fmaf(av[i].y, bv[j].y, s);
            s = fmaf(av[i].z, bv[j].z, s);
            acc[i][j] = fmaf(av[i].w, bv[j].w, s);
          }
      }
    }
  }
  __syncthreads();
  if (active){
    #pragma unroll
    for (int e=0;e<16;e++) Xs[(tile*16 + e)*12 + seg] = acc[e>>2][e&3];
  }
  if (tid < 128){ const int s = tid>>4, n = tid&15; sB[s][n] = xdbl[(gbase + s)*XDC + 48 + n]; }
  __syncthreads();
  for (int o = tid; o < 336; o += 256){
    const int tl = o >> 4, e = o & 15;
    int tt = tl, ti2 = 0;
    while (tt >= 6 - ti2){ tt -= 6 - ti2; ti2++; }
    const int tj2 = ti2 + tt;
    const int i = ti2*4 + (e>>2), j = tj2*4 + (e&3);
    float s = 0.f;
    #pragma unroll
    for (int sg=0; sg<12; sg++) s += Xs[o*12 + sg];
    Ms[i][j] = s; Ms[j][i] = s;
  }
  __syncthreads();

  // NS phase: 256 threads = full 16x16 (i,j); R in register, recurrence over t
  const int i = tid >> 4, j = tid & 15;
  float Rreg = Ms[i][j];
  constexpr float PB[9] = {1.f, 0.9f, 0.81f, 0.729f, 0.6561f, 0.59049f,
                           0.531441f, 0.4782969f, 0.43046721f};
  const size_t qbase = ((size_t)(b*CC + c)*TT)*256;
  #pragma unroll
  for (int t=0;t<TT;t++){
    float p_i = PB[t]*Ms[i][16+t];
    float p_j = PB[t]*Ms[j][16+t];
    #pragma unroll
    for (int r=0;r<t;r++){
      const float gg = Ms[16+r][16+t];
      p_i = fmaf(PB[t-1-r]*gg, sB[r][i], p_i);
      p_j = fmaf(PB[t-1-r]*gg, sB[r][j], p_j);
    }
    const float bi = sB[t][i], bj = sB[t][j];
    const float gtt = Ms[16+t][16+t];
    Rreg = BETA*BETA*Rreg + BETA*(p_i*bj + bi*p_j) + gtt*bi*bj;
    Rm[i][j] = Rreg;
    __syncthreads();
    float tr = 0.f;
    #pragma unroll
    for (int k=0;k<16;k++) tr += Rm[k][k];
    const float nu = sqrtf(tr) + 1e-7f;
    const float inv_nu = 1.f/nu;
    const float inv2 = inv_nu*inv_nu;
    const float inv4 = inv2*inv2;
    float a2v = 0.f;
    #pragma unroll
    for (int k=0;k<16;k++) a2v = fmaf(Rm[i][k], Rm[k][j], a2v);
    float q = NSB*inv2*Rreg + NSC*inv4*a2v;
    if (i == j) q += NSA;
    Qg[qbase + t*256 + tid] = q * inv_nu;
    __syncthreads();
  }
}

// ---------------- apply_k: barrier-free in-chunk scan, 1 d-row per thread ----------------
__global__ __launch_bounds__(256) void apply_k(
    const float* __restrict__ vst, const float* __restrict__ dt,
    const float* __restrict__ xcp, const float* __restrict__ xdbl,
    const float* __restrict__ Qg, const float* __restrict__ A_log,
    float* __restrict__ ylocal, float* __restrict__ hend)
{
  const int c = blockIdx.x, b = blockIdx.y, z = blockIdx.z;
  const int tid = threadIdx.x;
  const int d = z*256 + tid;
  __shared__ float sQ[8*256];
  __shared__ float sBC[8][32];

  const size_t qbase = ((size_t)(b*CC + c)*TT)*256;
  #pragma unroll
  for (int q=0;q<8;q++) sQ[q*256 + tid] = Qg[qbase + q*256 + tid];
  {
    const int s = tid >> 5, idx = tid & 31;
    sBC[s][idx] = xdbl[(size_t)(b*SEQL + c*TT + s)*XDC + 48 + idx];
  }
  __syncthreads();

  float v[16], h[16], Ar[16];
  {
    const float* vs = vst + ((size_t)(b*CC + c)*NDS)*DI + d;
    const float* arow = A_log + (size_t)d*NDS;
    #pragma unroll
    for (int n=0;n<16;n++){
      v[n] = vs[(size_t)n*DI];
      h[n] = 0.f;
      Ar[n] = -__expf(arow[n]) * LOG2E;
    }
  }

  for (int t=0;t<TT;t++){
    const size_t g = (size_t)(b*SEQL + c*TT + t);
    const float dtv = dt[g*DI + d];
    const float wv  = dtv * xcp[g*DI + d];
    #pragma unroll
    for (int n=0;n<16;n++) v[n] = fmaf(BETA, v[n], wv*sBC[t][n]);
    float un[16];
    #pragma unroll
    for (int n=0;n<16;n++) un[n] = 0.f;
    const float* qt = sQ + t*256;
    #pragma unroll
    for (int k=0;k<16;k++){
      const float vk = v[k];
      const float4 q0 = *(const float4*)(qt + k*16);
      const float4 q1 = *(const float4*)(qt + k*16 + 4);
      const float4 q2 = *(const float4*)(qt + k*16 + 8);
      const float4 q3 = *(const float4*)(qt + k*16 + 12);
      un[0]=fmaf(vk,q0.x,un[0]); un[1]=fmaf(vk,q0.y,un[1]); un[2]=fmaf(vk,q0.z,un[2]); un[3]=fmaf(vk,q0.w,un[3]);
      un[4]=fmaf(vk,q1.x,un[4]); un[5]=fmaf(vk,q1.y,un[5]); un[6]=fmaf(vk,q1.z,un[6]); un[7]=fmaf(vk,q1.w,un[7]);
      un[8]=fmaf(vk,q2.x,un[8]); un[9]=fmaf(vk,q2.y,un[9]); un[10]=fmaf(vk,q2.z,un[10]); un[11]=fmaf(vk,q2.w,un[11]);
      un[12]=fmaf(vk,q3.x,un[12]); un[13]=fmaf(vk,q3.y,un[13]); un[14]=fmaf(vk,q3.z,un[14]); un[15]=fmaf(vk,q3.w,un[15]);
    }
    float y = 0.f;
    #pragma unroll
    for (int n=0;n<16;n++){
      const float e = exp2f(dtv*Ar[n]);
      h[n] = fmaf(e, h[n], un[n]);
      y = fmaf(h[n], sBC[t][16+n], y);
    }
    ylocal[g*DI + d] = y;
  }
  float* he = hend + ((size_t)(b*CC + c)*NDS)*DI + d;
  #pragma unroll
  for (int n=0;n<16;n++) he[(size_t)n*DI] = h[n];
}

// ---------------- pass 4: combine h chunk-starts ----------------
__global__ void hcomb_k(const float* __restrict__ hend, const float* __restrict__ S,
                        const float* __restrict__ A_log, float* __restrict__ hst)
{
  const int d = blockIdx.x*256 + threadIdx.x;
  const int n = blockIdx.y, b = blockIdx.z;
  const float An = -__expf(A_log[(size_t)d*NDS + n]);
  const size_t stride = (size_t)NDS*DI;
  size_t idx  = ((size_t)(b*CC)*NDS + n)*DI + d;
  size_t sidx = (size_t)(b*CC)*DI + d;
  float hv = 0.f;
  for (int c=0;c<CC;c++){
    hst[idx] = hv;
    hv = fmaf(__expf(An * S[sidx]), hv, hend[idx]);
    idx += stride; sidx += DI;
  }
}

// ---------------- pass 5: y epilogue -> bf16 gated output ----------------
__global__ void yepi_k(const float* __restrict__ ylocal, const float* __restrict__ hst,
                       const float* __restrict__ cumdt, const float* __restrict__ xdbl,
                       const float* __restrict__ A_log, const float* __restrict__ Dv,
                       const float* __restrict__ xcp, const float* __restrict__ xz,
                       unsigned short* __restrict__ ybf)
{
  const int d = blockIdx.x*256 + threadIdx.x;
  const int g = blockIdx.y;
  const int b = g >> 9, t = g & (SEQL-1);
  const int c = t / TT;
  const float ddt = cumdt[(size_t)g*DI + d];
  const float* hs = hst + ((size_t)(b*CC + c)*NDS)*DI + d;
  const float* ar = A_log + (size_t)d*NDS;
  float corr = 0.f;
  #pragma unroll
  for (int n=0;n<16;n++){
    float An = -__expf(ar[n]);
    float Cn = xdbl[(size_t)g*XDC + 64 + n];
    corr = fmaf(hs[(size_t)n*DI] * __expf(An*ddt), Cn, corr);
  }
  float y = ylocal[(size_t)g*DI + d] + corr + Dv[d]*xcp[(size_t)g*DI + d];
  float z = xz[(size_t)g*(2*DI) + DI + d];
  ybf[(size_t)g*DI + d] = bfr(y * silu_(z));
}

// ============================== host ==============================
extern "C" void kernel_launch(void* const* d_in, const int* in_sizes, int n_in,
                              void* d_out, int out_size, void* d_ws, size_t ws_size,
                              hipStream_t stream)
{
  (void)in_sizes; (void)n_in; (void)out_size; (void)ws_size;
  const float* x      = (const float*)d_in[0];
  const float* in_w   = (const float*)d_in[1];
  const float* conv_w = (const float*)d_in[2];
  const float* conv_b = (const float*)d_in[3];
  const float* xp_w   = (const float*)d_in[4];
  const float* dtp_w  = (const float*)d_in[5];
  const float* dtp_b  = (const float*)d_in[6];
  const float* A_log  = (const float*)d_in[7];
  const float* Dp     = (const float*)d_in[8];
  const float* out_w  = (const float*)d_in[9];
  const float* norm_w = (const float*)d_in[10];
  const float* fnorm  = (const float*)d_in[11];

  const float betaT = powf(BETA, (float)TT);
  const int skx = 8, skout = 4;

  float* w0 = (float*)d_ws; size_t off = 0;
  auto alloc = [&](size_t n)->float*{ float* p = w0 + off; off += (n + 63) & ~(size_t)63; return p; };
  float* xa     = alloc((size_t)NT*DM);
  float* xb     = alloc((size_t)NT*DM);
  float* bfA    = alloc((size_t)NT*DI/2);       // bf16 A-matrices (xnb then ybf)
  float* xz     = alloc((size_t)NT*2*DI);
  float* xcb    = alloc((size_t)NT*DI);
  float* xdbl   = alloc((size_t)NT*XDC);
  float* dtb    = alloc((size_t)NT*DI);
  float* cumdt  = alloc((size_t)NT*DI);
  float* ylocal = alloc((size_t)NT*DI);
  float* Sbuf   = alloc((size_t)NB*CC*DI);
  float* Qg     = alloc((size_t)NB*CC*TT*256);
  float* big1   = alloc((size_t)NB*CC*NDS*DI);  // x_proj partials / Vagg / hend / out_proj partials
  float* big2   = alloc((size_t)NB*CC*NDS*DI);  // wbf / vst / hst / wbf(out)

  unsigned short* xnb = (unsigned short*)bfA;   // [NT][DM]
  unsigned short* ybf = (unsigned short*)bfA;   // [NT][DI]
  unsigned short* wbf = (unsigned short*)big2;  // bf16 weights (lifetimes disjoint from vst/hst)
  float* partb = big1;

  const float* xcur = x;
  float* nxt = xa;
  for (int l=0; l<2; l++){
    const float* inw_l = in_w   + (size_t)l*2*DI*DM;
    const float* cw_l  = conv_w + (size_t)l*DI*4;
    const float* cb_l  = conv_b + (size_t)l*DI;
    const float* xpw_l = xp_w   + (size_t)l*XDC*DI;
    const float* dtw_l = dtp_w  + (size_t)l*DI*DTR;
    const float* dtbi  = dtp_b  + (size_t)l*DI;
    const float* al_l  = A_log  + (size_t)l*DI*NDS;
    const float* d_l   = Dp     + (size_t)l*DI;
    const float* ow_l  = out_w  + (size_t)l*DM*DI;
    const float* nw_l  = norm_w + (size_t)l*DM;

    castbf_k<<<dim3((2*DI*DM/4+255)/256), dim3(256), 0, stream>>>(inw_l, wbf, 2*DI*DM/4);
    rms_k<1><<<dim3(NT), dim3(256), 0, stream>>>(xcur, nw_l, xnb);
    gemm_mf<0><<<dim3(2*DI/128, NT/128, 1), dim3(256), 0, stream>>>(
        xnb, DM, wbf, DM, xz, nullptr, NT, 2*DI, DM, 1);
    conv_k<<<dim3(DI/256, NT), dim3(256), 0, stream>>>(xz, cw_l, cb_l, xcb);
    gemm64<0><<<dim3((XDC+63)/64, NT/64, skx), dim3(256), 0, stream>>>(
        xcb, DI, xpw_l, DI, xdbl, partb, nullptr, NT, XDC, DI, skx);
    reduce_k<0><<<dim3((NT*XDC+255)/256), dim3(256), 0, stream>>>(partb, xdbl, nullptr, NT*XDC, skx);
    gemm64<1><<<dim3(DI/64, NT/64, 1), dim3(256), 0, stream>>>(
        xdbl, XDC, dtw_l, DTR, dtb, partb, dtbi, NT, DI, DTR, 1);
    vagg_k<<<dim3(DI/256, CC, NB), dim3(256), 0, stream>>>(dtb, xcb, xdbl, big1, Sbuf, cumdt);
    vcomb_k<<<dim3(DI/256, NDS, NB), dim3(256), 0, stream>>>(big1, big2, betaT);
    gram_k<<<dim3(CC, NB), dim3(256), 0, stream>>>(big2, dtb, xcb, xdbl, Qg);
    apply_k<<<dim3(CC, NB, DI/256), dim3(256), 0, stream>>>(
        big2, dtb, xcb, xdbl, Qg, al_l, ylocal, big1);
    hcomb_k<<<dim3(DI/256, NDS, NB), dim3(256), 0, stream>>>(big1, Sbuf, al_l, big2);
    yepi_k<<<dim3(DI/256, NT), dim3(256), 0, stream>>>(ylocal, big2, cumdt, xdbl, al_l, d_l, xcb, xz, ybf);
    castbf_k<<<dim3((DM*DI/4+255)/256), dim3(256), 0, stream>>>(ow_l, wbf, DM*DI/4);
    gemm_mf<0><<<dim3(DM/128, NT/128, skout), dim3(256), 0, stream>>>(
        ybf, DI, wbf, DI, nxt, partb, NT, DM, DI, skout);
    reduce_k<2><<<dim3((NT*DM+255)/256), dim3(256), 0, stream>>>(partb, nxt, xcur, NT*DM, skout);
    xcur = nxt; nxt = xb;
  }
  rms_k<0><<<dim3(NT), dim3(256), 0, stream>>>(xcur, fnorm, (float*)d_out);
}

// Round 9
// 423.401 us; speedup vs baseline: 1.4951x; 1.0594x over previous
//
#include <hip/hip_runtime.h>
#include <math.h>

#define DM   768
#define DI   1536
#define NDS  16
#define DTR  48
#define XDC  80
#define XPN  128
#define NB   2
#define SEQL 512
#define NT   (NB*SEQL)
#define CC   64
#define TT   8
#define BETA 0.9f
#define NSA  3.4445f
#define NSB  (-4.775f)
#define NSC  2.0315f
#define LOG2E 1.4426950408889634f
#define GKH  768
#define GKS  772

typedef __attribute__((ext_vector_type(8))) short short8v;
typedef __attribute__((ext_vector_type(4))) float f32x4;

__device__ __forceinline__ float silu_(float x){ return x / (1.f + __expf(-x)); }
__device__ __forceinline__ unsigned short bfr(float x){
  unsigned u = __float_as_uint(x);
  return (unsigned short)((u + 0x7fffu + ((u>>16)&1u)) >> 16);
}
__device__ __forceinline__ void gl_lds16(const unsigned short* g, unsigned short* l){
  __builtin_amdgcn_global_load_lds((const __attribute__((address_space(1))) void*)g,
                                   (__attribute__((address_space(3))) void*)l, 16, 0, 0);
}

// ---------------- rmsnorm (input layer only): f32 in -> bf16 out ----------------
__global__ void rms_k(const float* __restrict__ X, const float* __restrict__ W,
                      unsigned short* __restrict__ O)
{
  const int g = blockIdx.x, tid = threadIdx.x;
  const float* xr = X + (size_t)g*DM;
  float x0 = xr[tid], x1 = xr[tid+256], x2 = xr[tid+512];
  float ss = x0*x0 + x1*x1 + x2*x2;
  #pragma unroll
  for (int m=1; m<=32; m<<=1) ss += __shfl_xor(ss, m);
  __shared__ float ws[4];
  if ((tid & 63) == 0) ws[tid>>6] = ss;
  __syncthreads();
  float sc = rsqrtf((ws[0]+ws[1]+ws[2]+ws[3])*(1.f/DM) + 1e-5f);
  unsigned short* o = O + (size_t)g*DM;
  o[tid]     = bfr(x0*sc*W[tid]);
  o[tid+256] = bfr(x1*sc*W[tid+256]);
  o[tid+512] = bfr(x2*sc*W[tid+512]);
}

// ---------------- f32 -> bf16 cast (vectorized) ----------------
__global__ void castbf_k(const float* __restrict__ in, unsigned short* __restrict__ out, int n4)
{
  const int i = blockIdx.x*256 + threadIdx.x;
  if (i >= n4) return;
  float4 v = ((const float4*)in)[i];
  ushort4 o;
  o.x = bfr(v.x); o.y = bfr(v.y); o.z = bfr(v.z); o.w = bfr(v.w);
  ((ushort4*)out)[i] = o;
}

// ---------------- x_proj weight: [2][80][DI] f32 -> [2][128][DI] bf16 zero-padded --------
__global__ void castpad_k(const float* __restrict__ in, unsigned short* __restrict__ out)
{
  const int i = blockIdx.x*256 + threadIdx.x;
  const int total = 2*XPN*DI/4;
  if (i >= total) return;
  const int l = i / (XPN*DI/4);
  const int r = i % (XPN*DI/4);
  const int row = r / (DI/4);
  const int k4 = r % (DI/4);
  ushort4 o = {0,0,0,0};
  if (row < XDC){
    float4 v = *(const float4*)(in + ((size_t)l*XDC + row)*DI + k4*4);
    o.x = bfr(v.x); o.y = bfr(v.y); o.z = bfr(v.z); o.w = bfr(v.w);
  }
  ((ushort4*)out)[i] = o;
}

// ---------------- bf16 MFMA GEMM (m97 structure): C = A * B^T ----------------
__global__ __launch_bounds__(256) void gemm_mf(
    const unsigned short* __restrict__ Abf, int lda,
    const unsigned short* __restrict__ Bbf, int ldb,
    float* __restrict__ Out, float* __restrict__ Part,
    int M, int N, int K, int SK)
{
  __shared__ unsigned short As[128*32];
  __shared__ unsigned short Bs[128*32];
  const int tid  = threadIdx.x;
  const int wid  = tid >> 6, lane = tid & 63;
  const int bm   = blockIdx.y*128, bn = blockIdx.x*128;
  const int kc   = K/SK, kBeg = blockIdx.z*kc, kEnd = kBeg + kc;
  const int wr   = (wid>>1)*64, wc = (wid&1)*64;

  f32x4 acc[4][4];
  #pragma unroll
  for (int m=0;m<4;m++)
    #pragma unroll
    for (int n=0;n<4;n++) acc[m][n] = (f32x4){0.f,0.f,0.f,0.f};

  const int e0 = (wid*2)*512 + lane*8;
  const int e1 = e0 + 512;
  const int r0 = e0 >> 5, k0e = e0 & 31;
  const int r1 = e1 >> 5, k1e = e1 & 31;
  const unsigned short* Ag0 = Abf + (size_t)(bm + r0)*lda + k0e;
  const unsigned short* Ag1 = Abf + (size_t)(bm + r1)*lda + k1e;
  const unsigned short* Bg0 = Bbf + (size_t)(bn + r0)*ldb + k0e;
  const unsigned short* Bg1 = Bbf + (size_t)(bn + r1)*ldb + k1e;

  int aoff[4], boff[4];
  #pragma unroll
  for (int m=0;m<4;m++) aoff[m] = (wr + m*16 + (lane&15))*32 + (lane>>4)*8;
  #pragma unroll
  for (int n=0;n<4;n++) boff[n] = (wc + n*16 + (lane&15))*32 + (lane>>4)*8;

  for (int k0 = kBeg; k0 < kEnd; k0 += 32){
    gl_lds16(Ag0 + k0, As + e0);
    gl_lds16(Ag1 + k0, As + e1);
    gl_lds16(Bg0 + k0, Bs + e0);
    gl_lds16(Bg1 + k0, Bs + e1);
    __syncthreads();
    short8v af[4], bfv[4];
    #pragma unroll
    for (int m=0;m<4;m++) af[m]  = *(const short8v*)(As + aoff[m]);
    #pragma unroll
    for (int n=0;n<4;n++) bfv[n] = *(const short8v*)(Bs + boff[n]);
    #pragma unroll
    for (int m=0;m<4;m++)
      #pragma unroll
      for (int n=0;n<4;n++)
        acc[m][n] = __builtin_amdgcn_mfma_f32_16x16x32_bf16(af[m], bfv[n], acc[m][n], 0, 0, 0);
    __syncthreads();
  }

  #pragma unroll
  for (int m=0;m<4;m++){
    const int rowb = bm + wr + m*16 + (lane>>4)*4;
    #pragma unroll
    for (int n=0;n<4;n++){
      const int col = bn + wc + n*16 + (lane&15);
      #pragma unroll
      for (int r=0;r<4;r++){
        const int row = rowb + r;
        if (SK == 1) Out[(size_t)row*N + col] = acc[m][n][r];
        else         Part[(size_t)blockIdx.z*M*N + (size_t)row*N + col] = acc[m][n][r];
      }
    }
  }
}

// ---------------- dt_proj: f32 64-tile GEMM + softplus + w = dt*xc ----------------
__global__ void gemm64w(const float* __restrict__ A, int lda,
                        const float* __restrict__ Bw, int ldb,
                        float* __restrict__ Out, float* __restrict__ wOut,
                        const float* __restrict__ bias, const float* __restrict__ xc,
                        int M, int N, int K)
{
  __shared__ float As[16][64], Bs[16][64];
  const int tid = threadIdx.x;
  const int bm = blockIdx.y*64, bn = blockIdx.x*64;
  const int lr = tid>>2, lk = (tid&3)<<2;
  const int tx = tid&15, ty = tid>>4;
  float acc[4][4];
  #pragma unroll
  for (int i=0;i<4;i++)
    #pragma unroll
    for (int j=0;j<4;j++) acc[i][j] = 0.f;
  const float* Ap = A + (size_t)(bm+lr)*lda + lk;
  const float* Bp = Bw + (size_t)(bn+lr)*ldb + lk;
  for (int k0=0; k0<K; k0+=16){
    float4 a0 = *(const float4*)(Ap + k0);
    float4 b0 = *(const float4*)(Bp + k0);
    __syncthreads();
    As[lk+0][lr]=a0.x; As[lk+1][lr]=a0.y; As[lk+2][lr]=a0.z; As[lk+3][lr]=a0.w;
    Bs[lk+0][lr]=b0.x; Bs[lk+1][lr]=b0.y; Bs[lk+2][lr]=b0.z; Bs[lk+3][lr]=b0.w;
    __syncthreads();
    #pragma unroll
    for (int kk=0;kk<16;kk++){
      float a[4], b[4];
      *(float4*)a = *(const float4*)&As[kk][ty*4];
      *(float4*)b = *(const float4*)&Bs[kk][tx*4];
      #pragma unroll
      for (int i=0;i<4;i++)
        #pragma unroll
        for (int j=0;j<4;j++) acc[i][j] = fmaf(a[i], b[j], acc[i][j]);
    }
  }
  #pragma unroll
  for (int i=0;i<4;i++){
    const int row = bm + ty*4 + i;
    #pragma unroll
    for (int j=0;j<4;j++){
      const int col = bn + tx*4 + j;
      float vv = acc[i][j] + bias[col];
      vv = fmaxf(vv,0.f) + log1pf(__expf(-fabsf(vv)));
      Out[(size_t)row*N+col]  = vv;
      wOut[(size_t)row*N+col] = vv * xc[(size_t)row*N+col];
    }
  }
}

// ---------------- x_proj split-K reduce: Part[z][NT][128] -> xdbl[NT][80] ----------------
__global__ void reducepad_k(const float* __restrict__ Part, float* __restrict__ Out)
{
  const int i = blockIdx.x*256 + threadIdx.x;
  if (i >= NT*XDC) return;
  const int row = i / XDC, col = i % XDC;
  float s = 0.f;
  #pragma unroll
  for (int z=0; z<8; z++) s += Part[(size_t)z*NT*XPN + (size_t)row*XPN + col];
  Out[i] = s;
}

// ---------------- out_proj reduce + residual + rmsnorm (fused) ----------------
// MODE 1: write nxt (f32 residual) + xnb (bf16 normed, weight W)
// MODE 2: write dout (f32 normed, weight W)
template<int MODE>
__global__ void reduce_rms_k(const float* __restrict__ Part, const float* __restrict__ res,
                             const float* __restrict__ W, float* __restrict__ nxt,
                             unsigned short* __restrict__ xnb, float* __restrict__ dout)
{
  const int g = blockIdx.x, tid = threadIdx.x;
  float s[3];
  #pragma unroll
  for (int j=0;j<3;j++){
    const int e = tid + j*256;
    float v = res[(size_t)g*DM + e];
    #pragma unroll
    for (int z=0;z<4;z++) v += Part[(size_t)z*NT*DM + (size_t)g*DM + e];
    s[j] = v;
    if (MODE==1) nxt[(size_t)g*DM + e] = v;
  }
  float ss = s[0]*s[0] + s[1]*s[1] + s[2]*s[2];
  #pragma unroll
  for (int m=1; m<=32; m<<=1) ss += __shfl_xor(ss, m);
  __shared__ float ws[4];
  if ((tid & 63) == 0) ws[tid>>6] = ss;
  __syncthreads();
  float sc = rsqrtf((ws[0]+ws[1]+ws[2]+ws[3])*(1.f/DM) + 1e-5f);
  #pragma unroll
  for (int j=0;j<3;j++){
    const int e = tid + j*256;
    if (MODE==1) xnb[(size_t)g*DM + e] = bfr(s[j]*sc*W[e]);
    else         dout[(size_t)g*DM + e] = s[j]*sc*W[e];
  }
}

// ---------------- causal depthwise conv (width 4) + bias + silu; f32 + bf16 out -------
__global__ void conv_k(const float* __restrict__ xz, const float* __restrict__ cw,
                       const float* __restrict__ cb, float* __restrict__ xc,
                       unsigned short* __restrict__ xc16)
{
  const int d = blockIdx.x*256 + threadIdx.x;
  const int g = blockIdx.y;
  const int b = g >> 9, t = g & (SEQL-1);
  float4 w4 = *(const float4*)(cw + (size_t)d*4);
  const float wk[4] = {w4.x, w4.y, w4.z, w4.w};
  const float* col = xz + ((size_t)b*SEQL)*(2*DI) + d;
  float acc = cb[d];
  #pragma unroll
  for (int k=0;k<4;k++){
    int tt = t - 3 + k;
    if (tt >= 0) acc = fmaf(wk[k], col[(size_t)tt*(2*DI)], acc);
  }
  const float r = silu_(acc);
  xc[(size_t)g*DI + d]   = r;
  xc16[(size_t)g*DI + d] = bfr(r);
}

// ---------------- pass 1: per-chunk v aggregates + dt prefix sums ----------------
__global__ void vagg_k(const float* __restrict__ dt, const float* __restrict__ wb,
                       const float* __restrict__ xdbl, float* __restrict__ Vagg,
                       float* __restrict__ S, float* __restrict__ cumdt)
{
  const int d = blockIdx.x*256 + threadIdx.x;
  const int c = blockIdx.y, b = blockIdx.z;
  float acc[16];
  #pragma unroll
  for (int n=0;n<16;n++) acc[n] = 0.f;
  float sdt = 0.f;
  for (int s=0;s<TT;s++){
    const int g = b*SEQL + c*TT + s;
    sdt += dt[(size_t)g*DI + d];
    cumdt[(size_t)g*DI + d] = sdt;
    const float w = wb[(size_t)g*DI + d];
    #pragma unroll
    for (int n=0;n<16;n++) acc[n] = fmaf(BETA, acc[n], w * xdbl[(size_t)g*XDC + 48 + n]);
  }
  const size_t base = ((size_t)(b*CC + c)*NDS)*DI + d;
  #pragma unroll
  for (int n=0;n<16;n++) Vagg[base + (size_t)n*DI] = acc[n];
  S[(size_t)(b*CC + c)*DI + d] = sdt;
}

// ---------------- pass 2: in-place Vagg -> v_start ----------------
__global__ void vcomb_k(float* V, float betaT)
{
  const int d = blockIdx.x*256 + threadIdx.x;
  const int n = blockIdx.y, b = blockIdx.z;
  const size_t stride = (size_t)NDS*DI;
  size_t idx = ((size_t)(b*CC)*NDS + n)*DI + d;
  float v = 0.f;
  for (int c=0;c<CC;c++){
    const float a = V[idx];
    V[idx] = v;
    v = fmaf(betaT, v, a);
    idx += stride;
  }
}

// ---------------- gram_k: register-tiled 24x24 Gram of X=[v0|W] + full NS -> Q ----------
__global__ __launch_bounds__(256) void gram_k(
    const float* __restrict__ vst, const float* __restrict__ wb,
    const float* __restrict__ xdbl, float* __restrict__ Qg)
{
  const int c = blockIdx.x, b = blockIdx.y;
  const int tid = threadIdx.x;
  __shared__ float Xs[24*GKS];
  __shared__ float Ms[24][25];
  __shared__ float sB[8][16];
  __shared__ float Rm[16][17];

  const size_t vbase = ((size_t)(b*CC + c)*NDS)*DI;
  const size_t gbase = (size_t)(b*SEQL + c*TT);

  const bool active = tid < 252;
  const int tile = tid / 12, seg = tid % 12;
  int ti = 0, tj = 0;
  {
    int tt = tile;
    if (active){ while (tt >= 6 - ti){ tt -= 6 - ti; ti++; } tj = ti + tt; }
  }
  const int i0 = ti*4, j0 = tj*4;
  const int ks = seg*64;
  float acc[4][4];
  #pragma unroll
  for (int i=0;i<4;i++)
    #pragma unroll
    for (int j=0;j<4;j++) acc[i][j] = 0.f;

  for (int pass = 0; pass < 2; pass++){
    const int koff = pass * GKH;
    __syncthreads();
    #pragma unroll
    for (int q = 0; q < 18; q++){
      const int p = tid + q*256;
      const int col = p / 192;
      const int kk  = (p % 192) * 4;
      float4 xv;
      if (col < 16) xv = *(const float4*)(vst + vbase + (size_t)col*DI + koff + kk);
      else          xv = *(const float4*)(wb + (gbase + (col-16))*DI + koff + kk);
      *(float4*)(Xs + col*GKS + kk) = xv;
    }
    __syncthreads();
    if (active){
      for (int k4 = 0; k4 < 64; k4 += 4){
        float4 av[4], bv[4];
        #pragma unroll
        for (int r=0;r<4;r++) av[r] = *(const float4*)(Xs + (i0+r)*GKS + ks + k4);
        #pragma unroll
        for (int r=0;r<4;r++) bv[r] = *(const float4*)(Xs + (j0+r)*GKS + ks + k4);
        #pragma unroll
        for (int i=0;i<4;i++)
          #pragma unroll
          for (int j=0;j<4;j++){
            float s = fmaf(av[i].x, bv[j].x, acc[i][j]);
            s = fmaf(av[i].y, bv[j].y, s);
            s = fmaf(av[i].z, bv[j].z, s);
            acc[i][j] = fmaf(av[i].w, bv[j].w, s);
          }
      }
    }
  }
  __syncthreads();
  if (active){
    #pragma unroll
    for (int e=0;e<16;e++) Xs[(tile*16 + e)*12 + seg] = acc[e>>2][e&3];
  }
  if (tid < 128){ const int s = tid>>4, n = tid&15; sB[s][n] = xdbl[(gbase + s)*XDC + 48 + n]; }
  __syncthreads();
  for (int o = tid; o < 336; o += 256){
    const int tl = o >> 4, e = o & 15;
    int tt = tl, ti2 = 0;
    while (tt >= 6 - ti2){ tt -= 6 - ti2; ti2++; }
    const int tj2 = ti2 + tt;
    const int i = ti2*4 + (e>>2), j = tj2*4 + (e&3);
    float s = 0.f;
    #pragma unroll
    for (int sg=0; sg<12; sg++) s += Xs[o*12 + sg];
    Ms[i][j] = s; Ms[j][i] = s;
  }
  __syncthreads();

  const int i = tid >> 4, j = tid & 15;
  float Rreg = Ms[i][j];
  constexpr float PB[9] = {1.f, 0.9f, 0.81f, 0.729f, 0.6561f, 0.59049f,
                           0.531441f, 0.4782969f, 0.43046721f};
  const size_t qbase = ((size_t)(b*CC + c)*TT)*256;
  #pragma unroll
  for (int t=0;t<TT;t++){
    float p_i = PB[t]*Ms[i][16+t];
    float p_j = PB[t]*Ms[j][16+t];
    #pragma unroll
    for (int r=0;r<t;r++){
      const float gg = Ms[16+r][16+t];
      p_i = fmaf(PB[t-1-r]*gg, sB[r][i], p_i);
      p_j = fmaf(PB[t-1-r]*gg, sB[r][j], p_j);
    }
    const float bi = sB[t][i], bj = sB[t][j];
    const float gtt = Ms[16+t][16+t];
    Rreg = BETA*BETA*Rreg + BETA*(p_i*bj + bi*p_j) + gtt*bi*bj;
    Rm[i][j] = Rreg;
    __syncthreads();
    float tr = 0.f;
    #pragma unroll
    for (int k=0;k<16;k++) tr += Rm[k][k];
    const float nu = sqrtf(tr) + 1e-7f;
    const float inv_nu = 1.f/nu;
    const float inv2 = inv_nu*inv_nu;
    const float inv4 = inv2*inv2;
    float a2v = 0.f;
    #pragma unroll
    for (int k=0;k<16;k++) a2v = fmaf(Rm[i][k], Rm[k][j], a2v);
    float q = NSB*inv2*Rreg + NSC*inv4*a2v;
    if (i == j) q += NSA;
    Qg[qbase + t*256 + tid] = q * inv_nu;
    __syncthreads();
  }
}

// ---------------- apply_k: barrier-free in-chunk scan; vh in-place vst -> hend --------
__global__ __launch_bounds__(256) void apply_k(
    float* vh, const float* __restrict__ dt,
    const float* __restrict__ wb, const float* __restrict__ xdbl,
    const float* __restrict__ Qg, const float* __restrict__ A_log,
    float* __restrict__ ylocal)
{
  const int c = blockIdx.x, b = blockIdx.y, z = blockIdx.z;
  const int tid = threadIdx.x;
  const int d = z*256 + tid;
  __shared__ float sQ[8*256];
  __shared__ float sBC[8][32];

  const size_t qbase = ((size_t)(b*CC + c)*TT)*256;
  #pragma unroll
  for (int q=0;q<8;q++) sQ[q*256 + tid] = Qg[qbase + q*256 + tid];
  {
    const int s = tid >> 5, idx = tid & 31;
    sBC[s][idx] = xdbl[(size_t)(b*SEQL + c*TT + s)*XDC + 48 + idx];
  }
  __syncthreads();

  float v[16], h[16], Ar[16];
  {
    float* vs = vh + ((size_t)(b*CC + c)*NDS)*DI + d;
    const float* arow = A_log + (size_t)d*NDS;
    #pragma unroll
    for (int n=0;n<16;n++){
      v[n] = vs[(size_t)n*DI];
      h[n] = 0.f;
      Ar[n] = -__expf(arow[n]) * LOG2E;
    }
  }

  for (int t=0;t<TT;t++){
    const size_t g = (size_t)(b*SEQL + c*TT + t);
    const float dtv = dt[g*DI + d];
    const float wv  = wb[g*DI + d];
    #pragma unroll
    for (int n=0;n<16;n++) v[n] = fmaf(BETA, v[n], wv*sBC[t][n]);
    float un[16];
    #pragma unroll
    for (int n=0;n<16;n++) un[n] = 0.f;
    const float* qt = sQ + t*256;
    #pragma unroll
    for (int k=0;k<16;k++){
      const float vk = v[k];
      const float4 q0 = *(const float4*)(qt + k*16);
      const float4 q1 = *(const float4*)(qt + k*16 + 4);
      const float4 q2 = *(const float4*)(qt + k*16 + 8);
      const float4 q3 = *(const float4*)(qt + k*16 + 12);
      un[0]=fmaf(vk,q0.x,un[0]); un[1]=fmaf(vk,q0.y,un[1]); un[2]=fmaf(vk,q0.z,un[2]); un[3]=fmaf(vk,q0.w,un[3]);
      un[4]=fmaf(vk,q1.x,un[4]); un[5]=fmaf(vk,q1.y,un[5]); un[6]=fmaf(vk,q1.z,un[6]); un[7]=fmaf(vk,q1.w,un[7]);
      un[8]=fmaf(vk,q2.x,un[8]); un[9]=fmaf(vk,q2.y,un[9]); un[10]=fmaf(vk,q2.z,un[10]); un[11]=fmaf(vk,q2.w,un[11]);
      un[12]=fmaf(vk,q3.x,un[12]); un[13]=fmaf(vk,q3.y,un[13]); un[14]=fmaf(vk,q3.z,un[14]); un[15]=fmaf(vk,q3.w,un[15]);
    }
    float y = 0.f;
    #pragma unroll
    for (int n=0;n<16;n++){
      const float e = exp2f(dtv*Ar[n]);
      h[n] = fmaf(e, h[n], un[n]);
      y = fmaf(h[n], sBC[t][16+n], y);
    }
    ylocal[g*DI + d] = y;
  }
  float* he = vh + ((size_t)(b*CC + c)*NDS)*DI + d;
  #pragma unroll
  for (int n=0;n<16;n++) he[(size_t)n*DI] = h[n];
}

// ---------------- pass 4: in-place hend -> h_start ----------------
__global__ void hcomb_k(float* H, const float* __restrict__ S,
                        const float* __restrict__ A_log)
{
  const int d = blockIdx.x*256 + threadIdx.x;
  const int n = blockIdx.y, b = blockIdx.z;
  const float An = -__expf(A_log[(size_t)d*NDS + n]);
  const size_t stride = (size_t)NDS*DI;
  size_t idx  = ((size_t)(b*CC)*NDS + n)*DI + d;
  size_t sidx = (size_t)(b*CC)*DI + d;
  float hv = 0.f;
  for (int c=0;c<CC;c++){
    const float a = H[idx];
    H[idx] = hv;
    hv = fmaf(__expf(An * S[sidx]), hv, a);
    idx += stride; sidx += DI;
  }
}

// ---------------- pass 5: y epilogue -> bf16 gated output ----------------
__global__ void yepi_k(const float* __restrict__ ylocal, const float* __restrict__ hst,
                       const float* __restrict__ cumdt, const float* __restrict__ xdbl,
                       const float* __restrict__ A_log, const float* __restrict__ Dv,
                       const float* __restrict__ xcp, const float* __restrict__ xz,
                       unsigned short* __restrict__ ybf)
{
  const int d = blockIdx.x*256 + threadIdx.x;
  const int g = blockIdx.y;
  const int b = g >> 9, t = g & (SEQL-1);
  const int c = t / TT;
  const float ddt = cumdt[(size_t)g*DI + d];
  const float* hs = hst + ((size_t)(b*CC + c)*NDS)*DI + d;
  const float* ar = A_log + (size_t)d*NDS;
  float corr = 0.f;
  #pragma unroll
  for (int n=0;n<16;n++){
    float An = -__expf(ar[n]);
    float Cn = xdbl[(size_t)g*XDC + 64 + n];
    corr = fmaf(hs[(size_t)n*DI] * __expf(An*ddt), Cn, corr);
  }
  float y = ylocal[(size_t)g*DI + d] + corr + Dv[d]*xcp[(size_t)g*DI + d];
  float z = xz[(size_t)g*(2*DI) + DI + d];
  ybf[(size_t)g*DI + d] = bfr(y * silu_(z));
}

// ============================== host ==============================
extern "C" void kernel_launch(void* const* d_in, const int* in_sizes, int n_in,
                              void* d_out, int out_size, void* d_ws, size_t ws_size,
                              hipStream_t stream)
{
  (void)in_sizes; (void)n_in; (void)out_size; (void)ws_size;
  const float* x      = (const float*)d_in[0];
  const float* in_w   = (const float*)d_in[1];
  const float* conv_w = (const float*)d_in[2];
  const float* conv_b = (const float*)d_in[3];
  const float* xp_w   = (const float*)d_in[4];
  const float* dtp_w  = (const float*)d_in[5];
  const float* dtp_b  = (const float*)d_in[6];
  const float* A_log  = (const float*)d_in[7];
  const float* Dp     = (const float*)d_in[8];
  const float* out_w  = (const float*)d_in[9];
  const float* norm_w = (const float*)d_in[10];
  const float* fnorm  = (const float*)d_in[11];

  const float betaT = powf(BETA, (float)TT);

  float* w0 = (float*)d_ws; size_t off = 0;
  auto alloc = [&](size_t n)->float*{ float* p = w0 + off; off += (n + 63) & ~(size_t)63; return p; };
  float* xa     = alloc((size_t)NT*DM);
  float* bfA    = alloc((size_t)NT*DI/2);        // xnb then ybf (sequential lifetimes)
  float* xz     = alloc((size_t)NT*2*DI);
  float* xcb    = alloc((size_t)NT*DI);
  float* xcbbF  = alloc((size_t)NT*DI/2);        // bf16 xc
  float* xdbl   = alloc((size_t)NT*XDC);
  float* dtb    = alloc((size_t)NT*DI);
  float* wbuf   = alloc((size_t)NT*DI);
  float* cumdt  = alloc((size_t)NT*DI);
  float* ylocal = alloc((size_t)NT*DI);
  float* Sbuf   = alloc((size_t)NB*CC*DI);
  float* Qg     = alloc((size_t)NB*CC*TT*256);
  float* big1   = alloc((size_t)NB*CC*NDS*DI);   // xp partials / Vagg->vst->hend->hst / out partials
  float* wInF   = alloc((size_t)2*2*DI*DM/2);    // bf16 in_w, both layers
  float* wOutF  = alloc((size_t)2*DM*DI/2);      // bf16 out_w, both layers
  float* wXpF   = alloc((size_t)2*XPN*DI/2);     // bf16 padded xp_w, both layers

  unsigned short* xnb  = (unsigned short*)bfA;
  unsigned short* ybf  = (unsigned short*)bfA;
  unsigned short* xcbb = (unsigned short*)xcbbF;
  unsigned short* wInb = (unsigned short*)wInF;
  unsigned short* wOutb= (unsigned short*)wOutF;
  unsigned short* wXpb = (unsigned short*)wXpF;
  float* partb = big1;

  // one-time weight casts (both layers)
  castbf_k<<<dim3((2*2*DI*DM/4+255)/256), dim3(256), 0, stream>>>(in_w, wInb, 2*2*DI*DM/4);
  castbf_k<<<dim3((2*DM*DI/4+255)/256), dim3(256), 0, stream>>>(out_w, wOutb, 2*DM*DI/4);
  castpad_k<<<dim3((2*XPN*DI/4+255)/256), dim3(256), 0, stream>>>(xp_w, wXpb);
  rms_k<<<dim3(NT), dim3(256), 0, stream>>>(x, norm_w, xnb);

  const float* xcur = x;
  for (int l=0; l<2; l++){
    const unsigned short* wIn_l  = wInb  + (size_t)l*2*DI*DM;
    const unsigned short* wOut_l = wOutb + (size_t)l*DM*DI;
    const unsigned short* wXp_l  = wXpb  + (size_t)l*XPN*DI;
    const float* cw_l  = conv_w + (size_t)l*DI*4;
    const float* cb_l  = conv_b + (size_t)l*DI;
    const float* dtw_l = dtp_w  + (size_t)l*DI*DTR;
    const float* dtbi  = dtp_b  + (size_t)l*DI;
    const float* al_l  = A_log  + (size_t)l*DI*NDS;
    const float* d_l   = Dp     + (size_t)l*DI;

    gemm_mf<<<dim3(2*DI/128, NT/128, 1), dim3(256), 0, stream>>>(
        xnb, DM, wIn_l, DM, xz, nullptr, NT, 2*DI, DM, 1);
    conv_k<<<dim3(DI/256, NT), dim3(256), 0, stream>>>(xz, cw_l, cb_l, xcb, xcbb);
    gemm_mf<<<dim3(XPN/128, NT/128, 8), dim3(256), 0, stream>>>(
        xcbb, DI, wXp_l, DI, nullptr, partb, NT, XPN, DI, 8);
    reducepad_k<<<dim3((NT*XDC+255)/256), dim3(256), 0, stream>>>(partb, xdbl);
    gemm64w<<<dim3(DI/64, NT/64, 1), dim3(256), 0, stream>>>(
        xdbl, XDC, dtw_l, DTR, dtb, wbuf, dtbi, xcb, NT, DI, DTR);
    vagg_k<<<dim3(DI/256, CC, NB), dim3(256), 0, stream>>>(dtb, wbuf, xdbl, big1, Sbuf, cumdt);
    vcomb_k<<<dim3(DI/256, NDS, NB), dim3(256), 0, stream>>>(big1, betaT);
    gram_k<<<dim3(CC, NB), dim3(256), 0, stream>>>(big1, wbuf, xdbl, Qg);
    apply_k<<<dim3(CC, NB, DI/256), dim3(256), 0, stream>>>(
        big1, dtb, wbuf, xdbl, Qg, al_l, ylocal);
    hcomb_k<<<dim3(DI/256, NDS, NB), dim3(256), 0, stream>>>(big1, Sbuf, al_l);
    yepi_k<<<dim3(DI/256, NT), dim3(256), 0, stream>>>(
        ylocal, big1, cumdt, xdbl, al_l, d_l, xcb, xz, ybf);
    gemm_mf<<<dim3(DM/128, NT/128, 4), dim3(256), 0, stream>>>(
        ybf, DI, wOut_l, DI, nullptr, partb, NT, DM, DI, 4);
    if (l == 0)
      reduce_rms_k<1><<<dim3(NT), dim3(256), 0, stream>>>(
          partb, xcur, norm_w + DM, xa, xnb, nullptr);
    else
      reduce_rms_k<2><<<dim3(NT), dim3(256), 0, stream>>>(
          partb, xcur, fnorm, nullptr, nullptr, (float*)d_out);
    xcur = xa;
  }
}